// Round 1
// baseline (75.011 us; speedup 1.0000x reference)
//
#include <hip/hip_runtime.h>
#include <math.h>

// Chamfer distance: B=16, N=M=2048, D=3, fp32. ONE fused kernel + 4-byte memset.
// Block = (combo, 64-src chunk), 1024 blocks = 4/CU (16 waves/CU).
// Stages ALL 2048 opposing points in LDS (SoA + |y|^2, 4-word pad per 64 words
//   => the 8 distinct broadcast float4 addresses per wave cover all 32 banks,
//   conflict-free). Thread owns SPT=8 src pts (regs) and scans a 64-pt opp
//   range (q = tid>>3 of 32 groups) => 2 VALU ops/pair (pk_fma + min3) with
//   8x LDS-read amortization, same inner loop as the 2-stage version.
// Cross-group min is IN-BLOCK (shfl_xor over the 8 in-wave q's, 1KB LDS across
//   the 4 waves) — eliminates the 4 MB partial round-trip, the latency-bound
//   stage-2 dispatch, and the inter-dispatch drain. No fences needed: every
//   block is fully self-sufficient; one atomicAdd(out) per block (device scope).

typedef float v2f __attribute__((ext_vector_type(2)));

#define NPTS   2048
#define NCOMBO 32          // 2 dirs x 16 batches
#define SRCB   64          // src points per block
#define SPT    8           // src points per thread
#define NQ     32          // opp scan groups per block (256*SPT/SRCB)
#define OPPT   (NPTS/NQ)   // 64 opp points scanned per thread
#define PAD(i) ((i) + (((i) >> 6) << 2))   // +4 words per 64 -> bank spread

__device__ __forceinline__ v2f pkfma(v2f a, v2f b, v2f c) {
#if __has_builtin(__builtin_elementwise_fma)
    return __builtin_elementwise_fma(a, b, c);
#else
    v2f d; d.x = fmaf(a.x, b.x, c.x); d.y = fmaf(a.y, b.y, c.y); return d;
#endif
}

__global__ __launch_bounds__(256, 4) void chamfer_fused(
    const float* __restrict__ preds,
    const float* __restrict__ tgts,
    float* __restrict__ out)
{
    __shared__ __align__(16) float qx[2176];   // 2048 + 128 pad words
    __shared__ __align__(16) float qy[2176];
    __shared__ __align__(16) float qz[2176];
    __shared__ __align__(16) float qw[2176];
    __shared__ float sm[4 * SRCB];             // per-wave partial minima

    const int combo = blockIdx.x & (NCOMBO - 1);
    const int chunk = blockIdx.x >> 5;         // 0..31
    const int dir   = combo >> 4;
    const int b     = combo & 15;

    const float* src = (dir ? tgts : preds) + (size_t)b * NPTS * 3;
    const float* opp = (dir ? preds : tgts) + (size_t)b * NPTS * 3;

    // Stage all 2048 opposing points (SoA, padded; |y|^2 in qw)
    #pragma unroll
    for (int p = 0; p < NPTS / 256; p++) {
        const int i = threadIdx.x + 256 * p;
        const float y0 = opp[3 * i + 0];
        const float y1 = opp[3 * i + 1];
        const float y2 = opp[3 * i + 2];
        const int pi = PAD(i);
        qx[pi] = y0;
        qy[pi] = y1;
        qz[pi] = y2;
        qw[pi] = y0 * y0 + y1 * y1 + y2 * y2;
    }

    const int q = threadIdx.x >> 3;   // opp range [64q, 64q+64)
    const int c = threadIdx.x & 7;    // src ownership group

    // 8 src points per thread; nn = -2*x duplicated for packed math
    v2f nn0[SPT], nn1[SPT], nn2[SPT];
    float m[SPT];
    #pragma unroll
    for (int k = 0; k < SPT; k++) {
        const int s = chunk * SRCB + c * SPT + k;
        const float a0 = -2.0f * src[3 * s + 0];
        const float a1 = -2.0f * src[3 * s + 1];
        const float a2 = -2.0f * src[3 * s + 2];
        nn0[k] = (v2f){a0, a0};
        nn1[k] = (v2f){a1, a1};
        nn2[k] = (v2f){a2, a2};
        m[k]   = INFINITY;
    }
    __syncthreads();

    const int base = q * 68;          // PAD(q*64); 16B-aligned
    #pragma unroll 2
    for (int g = 0; g < OPPT / 4; g++) {
        const float4 X = *(const float4*)&qx[base + 4 * g];
        const float4 Y = *(const float4*)&qy[base + 4 * g];
        const float4 Z = *(const float4*)&qz[base + 4 * g];
        const float4 W = *(const float4*)&qw[base + 4 * g];
        const v2f Xa = {X.x, X.y}, Xb = {X.z, X.w};
        const v2f Ya = {Y.x, Y.y}, Yb = {Y.z, Y.w};
        const v2f Za = {Z.x, Z.y}, Zb = {Z.z, Z.w};
        const v2f Wa = {W.x, W.y}, Wb = {W.z, W.w};
        #pragma unroll
        for (int k = 0; k < SPT; k++) {
            const v2f sa = pkfma(nn0[k], Xa, pkfma(nn1[k], Ya, pkfma(nn2[k], Za, Wa)));
            m[k] = fminf(fminf(m[k], sa.x), sa.y);        // v_min3_f32
            const v2f sb = pkfma(nn0[k], Xb, pkfma(nn1[k], Yb, pkfma(nn2[k], Zb, Wb)));
            m[k] = fminf(fminf(m[k], sb.x), sb.y);        // v_min3_f32
        }
    }

    // Min over the 32 q-groups: 8 in-wave q's via shfl_xor (bits 3..5 of lane),
    // then the 4 waves via 1KB LDS.
    #pragma unroll
    for (int k = 0; k < SPT; k++) {
        float v = m[k];
        v = fminf(v, __shfl_xor(v, 8, 64));
        v = fminf(v, __shfl_xor(v, 16, 64));
        v = fminf(v, __shfl_xor(v, 32, 64));
        m[k] = v;
    }
    const int lane = threadIdx.x & 63;
    const int wid  = threadIdx.x >> 6;
    if (lane < 8) {
        #pragma unroll
        for (int k = 0; k < SPT; k++)
            sm[wid * SRCB + c * SPT + k] = m[k];
    }
    __syncthreads();

    // Wave 0: finalize 64 src minima, add |x|^2, block-sum, one atomicAdd.
    if (threadIdx.x < 64) {
        const int off = (threadIdx.x & 7) * SPT + (threadIdx.x >> 3);
        float mn = fminf(fminf(sm[off],            sm[SRCB + off]),
                         fminf(sm[2 * SRCB + off], sm[3 * SRCB + off]));
        const int s = chunk * SRCB + off;
        const float x0 = src[3 * s + 0];
        const float x1 = src[3 * s + 1];
        const float x2 = src[3 * s + 2];
        float val = x0 * x0 + x1 * x1 + x2 * x2 + mn;
        #pragma unroll
        for (int o = 32; o > 0; o >>= 1)
            val += __shfl_down(val, o, 64);
        if (threadIdx.x == 0) atomicAdd(out, val);
    }
}

extern "C" void kernel_launch(void* const* d_in, const int* in_sizes, int n_in,
                              void* d_out, int out_size, void* d_ws, size_t ws_size,
                              hipStream_t stream) {
    const float* preds = (const float*)d_in[0];
    const float* tgts  = (const float*)d_in[1];
    float* out = (float*)d_out;

    hipMemsetAsync(out, 0, sizeof(float), stream);   // graph-capturable fill node
    chamfer_fused<<<NCOMBO * 32, 256, 0, stream>>>(preds, tgts, out);
}

// Round 2
// 67.194 us; speedup vs baseline: 1.1163x; 1.1163x over previous
//
#include <hip/hip_runtime.h>
#include <math.h>

// Chamfer distance: B=16, N=M=2048, D=3, fp32. Fused main kernel + tiny reduce.
// R1 post-mortem: fusing with 1024 same-address device-scope atomicAdds from
//   perfectly co-resident, uniform-work blocks regressed 70.7 -> 75.0 us —
//   the atomics arrive as one burst and serialize at the cross-XCD coherence
//   point (~10-20 ns each => 10-20 us tail). This round: SAME main loop, but
//   each block does ONE plain coalesced store of its partial sum to d_ws;
//   a 1-block reduce kernel sums 1024 floats and writes out[0] (no memset
//   node, no atomics anywhere).
// Block = (combo, 64-src chunk), 1024 blocks = 4/CU (16 waves/CU).
// Stages ALL 2048 opposing points in LDS (SoA + |y|^2, 4-word pad per 64 words
//   => the 8 distinct broadcast float4 addresses per wave cover all 32 banks,
//   conflict-free). Thread owns SPT=8 src pts (regs) and scans a 64-pt opp
//   range => 2 VALU ops/pair (pk_fma + min3) with 8x LDS-read amortization.

typedef float v2f __attribute__((ext_vector_type(2)));

#define NPTS   2048
#define NCOMBO 32          // 2 dirs x 16 batches
#define SRCB   64          // src points per block
#define SPT    8           // src points per thread
#define NQ     32          // opp scan groups per block (256*SPT/SRCB)
#define OPPT   (NPTS/NQ)   // 64 opp points scanned per thread
#define NBLK   (NCOMBO * 32)
#define PAD(i) ((i) + (((i) >> 6) << 2))   // +4 words per 64 -> bank spread

__device__ __forceinline__ v2f pkfma(v2f a, v2f b, v2f c) {
#if __has_builtin(__builtin_elementwise_fma)
    return __builtin_elementwise_fma(a, b, c);
#else
    v2f d; d.x = fmaf(a.x, b.x, c.x); d.y = fmaf(a.y, b.y, c.y); return d;
#endif
}

__global__ __launch_bounds__(256, 4) void chamfer_fused(
    const float* __restrict__ preds,
    const float* __restrict__ tgts,
    float* __restrict__ bsum)
{
    __shared__ __align__(16) float qx[2176];   // 2048 + 128 pad words
    __shared__ __align__(16) float qy[2176];
    __shared__ __align__(16) float qz[2176];
    __shared__ __align__(16) float qw[2176];
    __shared__ float sm[4 * SRCB];             // per-wave partial minima

    const int combo = blockIdx.x & (NCOMBO - 1);
    const int chunk = blockIdx.x >> 5;         // 0..31
    const int dir   = combo >> 4;
    const int b     = combo & 15;

    const float* src = (dir ? tgts : preds) + (size_t)b * NPTS * 3;
    const float* opp = (dir ? preds : tgts) + (size_t)b * NPTS * 3;

    // Stage all 2048 opposing points (SoA, padded; |y|^2 in qw)
    #pragma unroll
    for (int p = 0; p < NPTS / 256; p++) {
        const int i = threadIdx.x + 256 * p;
        const float y0 = opp[3 * i + 0];
        const float y1 = opp[3 * i + 1];
        const float y2 = opp[3 * i + 2];
        const int pi = PAD(i);
        qx[pi] = y0;
        qy[pi] = y1;
        qz[pi] = y2;
        qw[pi] = y0 * y0 + y1 * y1 + y2 * y2;
    }

    const int q = threadIdx.x >> 3;   // opp range [64q, 64q+64)
    const int c = threadIdx.x & 7;    // src ownership group

    // 8 src points per thread; nn = -2*x duplicated for packed math
    v2f nn0[SPT], nn1[SPT], nn2[SPT];
    float m[SPT];
    #pragma unroll
    for (int k = 0; k < SPT; k++) {
        const int s = chunk * SRCB + c * SPT + k;
        const float a0 = -2.0f * src[3 * s + 0];
        const float a1 = -2.0f * src[3 * s + 1];
        const float a2 = -2.0f * src[3 * s + 2];
        nn0[k] = (v2f){a0, a0};
        nn1[k] = (v2f){a1, a1};
        nn2[k] = (v2f){a2, a2};
        m[k]   = INFINITY;
    }
    __syncthreads();

    const int base = q * 68;          // PAD(q*64); 16B-aligned
    #pragma unroll 2
    for (int g = 0; g < OPPT / 4; g++) {
        const float4 X = *(const float4*)&qx[base + 4 * g];
        const float4 Y = *(const float4*)&qy[base + 4 * g];
        const float4 Z = *(const float4*)&qz[base + 4 * g];
        const float4 W = *(const float4*)&qw[base + 4 * g];
        const v2f Xa = {X.x, X.y}, Xb = {X.z, X.w};
        const v2f Ya = {Y.x, Y.y}, Yb = {Y.z, Y.w};
        const v2f Za = {Z.x, Z.y}, Zb = {Z.z, Z.w};
        const v2f Wa = {W.x, W.y}, Wb = {W.z, W.w};
        #pragma unroll
        for (int k = 0; k < SPT; k++) {
            const v2f sa = pkfma(nn0[k], Xa, pkfma(nn1[k], Ya, pkfma(nn2[k], Za, Wa)));
            m[k] = fminf(fminf(m[k], sa.x), sa.y);        // v_min3_f32
            const v2f sb = pkfma(nn0[k], Xb, pkfma(nn1[k], Yb, pkfma(nn2[k], Zb, Wb)));
            m[k] = fminf(fminf(m[k], sb.x), sb.y);        // v_min3_f32
        }
    }

    // Min over the 32 q-groups: 8 in-wave q's via shfl_xor (bits 3..5 of lane),
    // then the 4 waves via 1KB LDS.
    #pragma unroll
    for (int k = 0; k < SPT; k++) {
        float v = m[k];
        v = fminf(v, __shfl_xor(v, 8, 64));
        v = fminf(v, __shfl_xor(v, 16, 64));
        v = fminf(v, __shfl_xor(v, 32, 64));
        m[k] = v;
    }
    const int lane = threadIdx.x & 63;
    const int wid  = threadIdx.x >> 6;
    if (lane < 8) {
        #pragma unroll
        for (int k = 0; k < SPT; k++)
            sm[wid * SRCB + c * SPT + k] = m[k];
    }
    __syncthreads();

    // Wave 0: finalize 64 src minima, add |x|^2, block-sum, ONE plain store.
    if (threadIdx.x < 64) {
        const int off = (threadIdx.x & 7) * SPT + (threadIdx.x >> 3);
        float mn = fminf(fminf(sm[off],            sm[SRCB + off]),
                         fminf(sm[2 * SRCB + off], sm[3 * SRCB + off]));
        const int s = chunk * SRCB + off;
        const float x0 = src[3 * s + 0];
        const float x1 = src[3 * s + 1];
        const float x2 = src[3 * s + 2];
        float val = x0 * x0 + x1 * x1 + x2 * x2 + mn;
        #pragma unroll
        for (int o = 32; o > 0; o >>= 1)
            val += __shfl_down(val, o, 64);
        if (threadIdx.x == 0) bsum[blockIdx.x] = val;
    }
}

__global__ __launch_bounds__(256) void chamfer_sum(
    const float* __restrict__ bsum,
    float* __restrict__ out)
{
    __shared__ float wsum[4];

    float val = bsum[threadIdx.x]         + bsum[threadIdx.x + 256]
              + bsum[threadIdx.x + 512]   + bsum[threadIdx.x + 768];

    #pragma unroll
    for (int o = 32; o > 0; o >>= 1)
        val += __shfl_down(val, o, 64);

    const int lane = threadIdx.x & 63;
    const int wid  = threadIdx.x >> 6;
    if (lane == 0) wsum[wid] = val;
    __syncthreads();
    if (threadIdx.x == 0)
        out[0] = wsum[0] + wsum[1] + wsum[2] + wsum[3];
}

extern "C" void kernel_launch(void* const* d_in, const int* in_sizes, int n_in,
                              void* d_out, int out_size, void* d_ws, size_t ws_size,
                              hipStream_t stream) {
    const float* preds = (const float*)d_in[0];
    const float* tgts  = (const float*)d_in[1];
    float* out  = (float*)d_out;
    float* bsum = (float*)d_ws;   // 1024 floats

    chamfer_fused<<<NBLK, 256, 0, stream>>>(preds, tgts, bsum);
    chamfer_sum<<<1, 256, 0, stream>>>(bsum, out);
}

// Round 3
// 65.728 us; speedup vs baseline: 1.1412x; 1.0223x over previous
//
#include <hip/hip_runtime.h>
#include <math.h>

// Chamfer distance: B=16, N=M=2048, D=3, fp32. Fused main kernel + tiny reduce.
// R2 post-mortem: all 3 rounds fit {fill 40us + ~20us 2-node graph overhead +
//   kernels at floor (~7us)}. Only surviving alternative: VGPR spill under the
//   forced 128-reg cap of __launch_bounds__(256,4) with the unroll-2 loop
//   (~110 live + temps). This round isolates that: unroll 1 + (256,2).
//   Live regs ~90 -> no spill possible; LDS (35.8 KB) still caps residency at
//   4 blocks/CU so occupancy is unchanged. Everything else byte-identical.
// Block = (combo, 64-src chunk), 1024 blocks = 4/CU (16 waves/CU).
// Stages ALL 2048 opposing points in LDS (SoA + |y|^2, 4-word pad per 64 words
//   => the 8 distinct broadcast float4 addresses per wave cover all 32 banks,
//   conflict-free). Thread owns SPT=8 src pts (regs), scans 64 opp pts =>
//   2 VALU ops/pair (pk_fma + min3) with 8x LDS-read amortization.

typedef float v2f __attribute__((ext_vector_type(2)));

#define NPTS   2048
#define NCOMBO 32          // 2 dirs x 16 batches
#define SRCB   64          // src points per block
#define SPT    8           // src points per thread
#define NQ     32          // opp scan groups per block (256*SPT/SRCB)
#define OPPT   (NPTS/NQ)   // 64 opp points scanned per thread
#define NBLK   (NCOMBO * 32)
#define PAD(i) ((i) + (((i) >> 6) << 2))   // +4 words per 64 -> bank spread

__device__ __forceinline__ v2f pkfma(v2f a, v2f b, v2f c) {
#if __has_builtin(__builtin_elementwise_fma)
    return __builtin_elementwise_fma(a, b, c);
#else
    v2f d; d.x = fmaf(a.x, b.x, c.x); d.y = fmaf(a.y, b.y, c.y); return d;
#endif
}

__global__ __launch_bounds__(256, 2) void chamfer_fused(
    const float* __restrict__ preds,
    const float* __restrict__ tgts,
    float* __restrict__ bsum)
{
    __shared__ __align__(16) float qx[2176];   // 2048 + 128 pad words
    __shared__ __align__(16) float qy[2176];
    __shared__ __align__(16) float qz[2176];
    __shared__ __align__(16) float qw[2176];
    __shared__ float sm[4 * SRCB];             // per-wave partial minima

    const int combo = blockIdx.x & (NCOMBO - 1);
    const int chunk = blockIdx.x >> 5;         // 0..31
    const int dir   = combo >> 4;
    const int b     = combo & 15;

    const float* src = (dir ? tgts : preds) + (size_t)b * NPTS * 3;
    const float* opp = (dir ? preds : tgts) + (size_t)b * NPTS * 3;

    // Stage all 2048 opposing points (SoA, padded; |y|^2 in qw)
    #pragma unroll
    for (int p = 0; p < NPTS / 256; p++) {
        const int i = threadIdx.x + 256 * p;
        const float y0 = opp[3 * i + 0];
        const float y1 = opp[3 * i + 1];
        const float y2 = opp[3 * i + 2];
        const int pi = PAD(i);
        qx[pi] = y0;
        qy[pi] = y1;
        qz[pi] = y2;
        qw[pi] = y0 * y0 + y1 * y1 + y2 * y2;
    }

    const int q = threadIdx.x >> 3;   // opp range [64q, 64q+64)
    const int c = threadIdx.x & 7;    // src ownership group

    // 8 src points per thread; nn = -2*x duplicated for packed math
    v2f nn0[SPT], nn1[SPT], nn2[SPT];
    float m[SPT];
    #pragma unroll
    for (int k = 0; k < SPT; k++) {
        const int s = chunk * SRCB + c * SPT + k;
        const float a0 = -2.0f * src[3 * s + 0];
        const float a1 = -2.0f * src[3 * s + 1];
        const float a2 = -2.0f * src[3 * s + 2];
        nn0[k] = (v2f){a0, a0};
        nn1[k] = (v2f){a1, a1};
        nn2[k] = (v2f){a2, a2};
        m[k]   = INFINITY;
    }
    __syncthreads();

    const int base = q * 68;          // PAD(q*64); 16B-aligned
    #pragma unroll 1
    for (int g = 0; g < OPPT / 4; g++) {
        const float4 X = *(const float4*)&qx[base + 4 * g];
        const float4 Y = *(const float4*)&qy[base + 4 * g];
        const float4 Z = *(const float4*)&qz[base + 4 * g];
        const float4 W = *(const float4*)&qw[base + 4 * g];
        const v2f Xa = {X.x, X.y}, Xb = {X.z, X.w};
        const v2f Ya = {Y.x, Y.y}, Yb = {Y.z, Y.w};
        const v2f Za = {Z.x, Z.y}, Zb = {Z.z, Z.w};
        const v2f Wa = {W.x, W.y}, Wb = {W.z, W.w};
        #pragma unroll
        for (int k = 0; k < SPT; k++) {
            const v2f sa = pkfma(nn0[k], Xa, pkfma(nn1[k], Ya, pkfma(nn2[k], Za, Wa)));
            m[k] = fminf(fminf(m[k], sa.x), sa.y);        // v_min3_f32
            const v2f sb = pkfma(nn0[k], Xb, pkfma(nn1[k], Yb, pkfma(nn2[k], Zb, Wb)));
            m[k] = fminf(fminf(m[k], sb.x), sb.y);        // v_min3_f32
        }
    }

    // Min over the 32 q-groups: 8 in-wave q's via shfl_xor (bits 3..5 of lane),
    // then the 4 waves via 1KB LDS.
    #pragma unroll
    for (int k = 0; k < SPT; k++) {
        float v = m[k];
        v = fminf(v, __shfl_xor(v, 8, 64));
        v = fminf(v, __shfl_xor(v, 16, 64));
        v = fminf(v, __shfl_xor(v, 32, 64));
        m[k] = v;
    }
    const int lane = threadIdx.x & 63;
    const int wid  = threadIdx.x >> 6;
    if (lane < 8) {
        #pragma unroll
        for (int k = 0; k < SPT; k++)
            sm[wid * SRCB + c * SPT + k] = m[k];
    }
    __syncthreads();

    // Wave 0: finalize 64 src minima, add |x|^2, block-sum, ONE plain store.
    if (threadIdx.x < 64) {
        const int off = (threadIdx.x & 7) * SPT + (threadIdx.x >> 3);
        float mn = fminf(fminf(sm[off],            sm[SRCB + off]),
                         fminf(sm[2 * SRCB + off], sm[3 * SRCB + off]));
        const int s = chunk * SRCB + off;
        const float x0 = src[3 * s + 0];
        const float x1 = src[3 * s + 1];
        const float x2 = src[3 * s + 2];
        float val = x0 * x0 + x1 * x1 + x2 * x2 + mn;
        #pragma unroll
        for (int o = 32; o > 0; o >>= 1)
            val += __shfl_down(val, o, 64);
        if (threadIdx.x == 0) bsum[blockIdx.x] = val;
    }
}

__global__ __launch_bounds__(256) void chamfer_sum(
    const float* __restrict__ bsum,
    float* __restrict__ out)
{
    __shared__ float wsum[4];

    float val = bsum[threadIdx.x]         + bsum[threadIdx.x + 256]
              + bsum[threadIdx.x + 512]   + bsum[threadIdx.x + 768];

    #pragma unroll
    for (int o = 32; o > 0; o >>= 1)
        val += __shfl_down(val, o, 64);

    const int lane = threadIdx.x & 63;
    const int wid  = threadIdx.x >> 6;
    if (lane == 0) wsum[wid] = val;
    __syncthreads();
    if (threadIdx.x == 0)
        out[0] = wsum[0] + wsum[1] + wsum[2] + wsum[3];
}

extern "C" void kernel_launch(void* const* d_in, const int* in_sizes, int n_in,
                              void* d_out, int out_size, void* d_ws, size_t ws_size,
                              hipStream_t stream) {
    const float* preds = (const float*)d_in[0];
    const float* tgts  = (const float*)d_in[1];
    float* out  = (float*)d_out;
    float* bsum = (float*)d_ws;   // 1024 floats

    chamfer_fused<<<NBLK, 256, 0, stream>>>(preds, tgts, bsum);
    chamfer_sum<<<1, 256, 0, stream>>>(bsum, out);
}